// Round 1
// baseline (284.879 us; speedup 1.0000x reference)
//
#include <hip/hip_runtime.h>
#include <cstdint>
#include <cstddef>

// Problem dims (fixed by the reference)
#define T_DIM 256
#define H_DIM 4096
#define I_DIM 14336
// groups: G1 = H/64 = 64, G2 = I/64 = 224; BK = 64 = GROUP_SIZE (1 group per K-tile)

typedef __attribute__((ext_vector_type(8))) short s8v;   // 8 bf16 = 4 VGPR (MFMA A/B frag)
typedef __attribute__((ext_vector_type(4))) float f4v;   // 4 f32  (MFMA C/D frag)

// Workspace layout
static constexpr size_t XS_BYTES   = (size_t)T_DIM * H_DIM * 2;   // x bf16 staged (2 MiB)
static constexpr size_t ACT_OFF    = XS_BYTES;
static constexpr size_t ACT_BYTES  = (size_t)T_DIM * I_DIM * 2;   // act bf16 staged (7 MiB)
static constexpr size_t PART_OFF   = ACT_OFF + ACT_BYTES;
static constexpr size_t PART_BYTES = 8ull * T_DIM * H_DIM * 4;    // 8 K-chunk partials (32 MiB)
static constexpr size_t WS_NEEDED  = PART_OFF + PART_BYTES;

__device__ __forceinline__ unsigned short f2bf(float f) {
    // round-to-nearest-even fp32 -> bf16
    unsigned u = __builtin_bit_cast(unsigned, f);
    u += 0x7fffu + ((u >> 16) & 1u);
    return (unsigned short)(u >> 16);
}

__device__ __forceinline__ void g2lds16(const void* g, void* l) {
    // async global->LDS, 16B/lane. LDS dest is wave-uniform base (+lane*16 in HW);
    // global src is per-lane.
    __builtin_amdgcn_global_load_lds(
        (const __attribute__((address_space(1))) unsigned int*)g,
        (__attribute__((address_space(3))) unsigned int*)l,
        16, 0, 0);
}

__device__ __forceinline__ s8v dq8(const int4 qa, const int4 qb, float s, float ns) {
    // w = (q - z)*s = q*s + (-z*s); ns = -z*s
    union { unsigned short u[8]; s8v v; } r;
    r.u[0] = f2bf(fmaf((float)qa.x, s, ns));
    r.u[1] = f2bf(fmaf((float)qa.y, s, ns));
    r.u[2] = f2bf(fmaf((float)qa.z, s, ns));
    r.u[3] = f2bf(fmaf((float)qa.w, s, ns));
    r.u[4] = f2bf(fmaf((float)qb.x, s, ns));
    r.u[5] = f2bf(fmaf((float)qb.y, s, ns));
    r.u[6] = f2bf(fmaf((float)qb.z, s, ns));
    r.u[7] = f2bf(fmaf((float)qb.w, s, ns));
    return r.v;
}

// ---------------------------------------------------------------------------
// k_prep: x fp32 [256,4096] -> bf16 staged, K-tile-major (64 tiles of [256][64])
// with XOR swizzle: within a tile, element (row,c) lives at byte
// (row*128 + c*2) ^ ((row&7)<<4). GEMM blocks then stage a whole 32 KiB tile
// with LINEAR global_load_lds and read fragments with the same XOR.
// ---------------------------------------------------------------------------
__global__ __launch_bounds__(256) void k_prep(const float* __restrict__ x,
                                              unsigned short* __restrict__ xs) {
    int gs   = blockIdx.x * 256 + threadIdx.x;   // 0..131071
    int kt   = gs >> 11;                         // K-tile (64 cols each)
    int rem  = gs & 2047;
    int row  = rem >> 3;                         // 0..255
    int slot = rem & 7;                          // 16B slot within row (8 bf16)
    const float* xp = x + (size_t)row * H_DIM + kt * 64 + slot * 8;
    float4 a = *(const float4*)xp;
    float4 b = *(const float4*)(xp + 4);
    union { unsigned short u[8]; s8v v; } r;
    r.u[0] = f2bf(a.x); r.u[1] = f2bf(a.y); r.u[2] = f2bf(a.z); r.u[3] = f2bf(a.w);
    r.u[4] = f2bf(b.x); r.u[5] = f2bf(b.y); r.u[6] = f2bf(b.z); r.u[7] = f2bf(b.w);
    size_t di = (size_t)kt * 16384 + (size_t)row * 64 + (size_t)((slot ^ (row & 7)) * 8);
    *(s8v*)(xs + di) = r.v;
}

// ---------------------------------------------------------------------------
// k_gemm1: fused gate/up GEMM. Block = full M=256 x BN=64 cols of I, K=4096.
// grid 224. 8 waves as 4(M)x2(N); per wave 64x32 out per matrix.
// acc: accg (w1 path) + accu (w3 path). Epilogue: silu(g)*u -> act staged bf16.
// ---------------------------------------------------------------------------
__global__ __launch_bounds__(512, 2) void k_gemm1(
    const int* __restrict__ w1q, const float* __restrict__ w1s, const float* __restrict__ w1z,
    const int* __restrict__ w3q, const float* __restrict__ w3s, const float* __restrict__ w3z,
    const unsigned short* __restrict__ xs, unsigned short* __restrict__ act)
{
    __shared__ unsigned char lds[49152];   // x: [0,32K) w1: [32K,40K) w3: [40K,48K)
    const int tid  = threadIdx.x;
    const int blk  = blockIdx.x;
    const int n0   = blk * 64;
    const int wid  = tid >> 6;
    const int lane = tid & 63;
    const int wr   = wid >> 1;             // 0..3  -> M base wr*64
    const int wc   = wid & 1;              // 0..1  -> N base wc*32
    const int lr   = lane & 15;
    const int lkb  = lane >> 4;            // k-block 0..3 (8 bf16 each)
    const int aswz = (lr & 7) << 4;        // fragment-read XOR (row&7 == lr&7)

    // weight staging: thread -> (row 0..63, 16B slot 0..7)
    const int srow  = tid >> 3;
    const int sslot = tid & 7;
    const size_t grow = (size_t)(n0 + srow) * H_DIM + (size_t)sslot * 8;
    const int wbyte = srow * 128 + ((sslot * 16) ^ ((srow & 7) << 4));
    const float* s1p = w1s + (size_t)(n0 + srow) * 64;
    const float* z1p = w1z + (size_t)(n0 + srow) * 64;
    const float* s3p = w3s + (size_t)(n0 + srow) * 64;
    const float* z3p = w3z + (size_t)(n0 + srow) * 64;

    f4v accg[4][2], accu[4][2];
    const f4v fz = {0.f, 0.f, 0.f, 0.f};
    #pragma unroll
    for (int i = 0; i < 4; ++i)
        #pragma unroll
        for (int j = 0; j < 2; ++j) { accg[i][j] = fz; accu[i][j] = fz; }

    const unsigned char* xsb = (const unsigned char*)xs;

    for (int kt = 0; kt < 64; ++kt) {
        // 1) async x tile (32 KiB linear; source is pre-swizzled)
        {
            const unsigned char* gsrc = xsb + (size_t)kt * 32768 + (size_t)wid * 1024
                                            + (size_t)lane * 16;
            unsigned char* ldst = lds + wid * 1024;   // wave-uniform
            #pragma unroll
            for (int j = 0; j < 4; ++j)
                g2lds16(gsrc + j * 8192, ldst + j * 8192);
        }
        // 2) reg-stage + dequant w1/w3 tiles (one scale/zero per row per K-tile)
        {
            const int4* p1 = (const int4*)(w1q + grow + (size_t)kt * 64);
            const int4* p3 = (const int4*)(w3q + grow + (size_t)kt * 64);
            int4 q1a = p1[0], q1b = p1[1];
            int4 q3a = p3[0], q3b = p3[1];
            float s1 = s1p[kt]; float ns1 = -z1p[kt] * s1;
            float s3 = s3p[kt]; float ns3 = -z3p[kt] * s3;
            *(s8v*)(lds + 32768 + wbyte) = dq8(q1a, q1b, s1, ns1);
            *(s8v*)(lds + 40960 + wbyte) = dq8(q3a, q3b, s3, ns3);
        }
        __syncthreads();   // barrier drain covers vmcnt (global_load_lds) + lgkm
        // 3) compute: 2 k-steps of 16x16x32, 32 MFMA/wave/tile
        #pragma unroll
        for (int kf = 0; kf < 2; ++kf) {
            const int kb = (kf * 64 + lkb * 16) ^ aswz;
            s8v a[4];
            #pragma unroll
            for (int mf = 0; mf < 4; ++mf)
                a[mf] = *(const s8v*)(lds + (wr * 64 + mf * 16 + lr) * 128 + kb);
            s8v b1[2], b3[2];
            #pragma unroll
            for (int nf = 0; nf < 2; ++nf) {
                const int rbo = (wc * 32 + nf * 16 + lr) * 128 + kb;
                b1[nf] = *(const s8v*)(lds + 32768 + rbo);
                b3[nf] = *(const s8v*)(lds + 40960 + rbo);
            }
            #pragma unroll
            for (int mf = 0; mf < 4; ++mf)
                #pragma unroll
                for (int nf = 0; nf < 2; ++nf) {
                    accg[mf][nf] = __builtin_amdgcn_mfma_f32_16x16x32_bf16(a[mf], b1[nf], accg[mf][nf], 0, 0, 0);
                    accu[mf][nf] = __builtin_amdgcn_mfma_f32_16x16x32_bf16(a[mf], b3[nf], accu[mf][nf], 0, 0, 0);
                }
        }
        __syncthreads();
    }

    // epilogue: act[t][n0+nl] = silu(g)*u, written in staged-swizzled layout
    // (this block's 64 cols ARE GEMM2's K-tile kt2 = blk)
    unsigned char* actb = (unsigned char*)act + (size_t)blk * 32768;
    #pragma unroll
    for (int mf = 0; mf < 4; ++mf)
        #pragma unroll
        for (int nf = 0; nf < 2; ++nf)
            #pragma unroll
            for (int r = 0; r < 4; ++r) {
                const int m  = wr * 64 + mf * 16 + lkb * 4 + r;   // D row
                const int nl = wc * 32 + nf * 16 + lr;            // D col
                float g = accg[mf][nf][r];
                float u = accu[mf][nf][r];
                float sg = g / (1.0f + __expf(-g));
                *(unsigned short*)(actb + ((m * 128 + nl * 2) ^ ((m & 7) << 4))) = f2bf(sg * u);
            }
}

// ---------------------------------------------------------------------------
// k_gemm2: out_partial[kc] = act[:, kc-chunk] @ w2[:, kc-chunk]^T.
// Block = M=256 x BN=128; grid = 32 N-blocks x 8 K-chunks (28 K-tiles each).
// 8 waves as 2(M)x4(N); per wave 128x32 out.
// ---------------------------------------------------------------------------
template<bool ATOMIC>
__global__ __launch_bounds__(512, 2) void k_gemm2(
    const int* __restrict__ w2q, const float* __restrict__ w2s, const float* __restrict__ w2z,
    const unsigned short* __restrict__ act, float* __restrict__ outp)
{
    __shared__ unsigned char lds[49152];   // act: [0,32K) w2: [32K,48K)
    const int tid  = threadIdx.x;
    const int nb   = blockIdx.x & 31;
    const int kc   = blockIdx.x >> 5;
    const int n0   = nb * 128;
    const int wid  = tid >> 6;
    const int lane = tid & 63;
    const int wr   = wid >> 2;             // 0..1 -> M base wr*128
    const int wc   = wid & 3;              // 0..3 -> N base wc*32
    const int lr   = lane & 15;
    const int lkb  = lane >> 4;
    const int aswz = (lr & 7) << 4;

    // staging: thread -> (row 0..127, two 16B slots)
    const int srow = tid >> 2;
    const int ss2  = (tid & 3) * 2;
    const size_t grow = (size_t)(n0 + srow) * I_DIM + (size_t)ss2 * 8;
    const int wb0 = srow * 128 + ((ss2 * 16)       ^ ((srow & 7) << 4));
    const int wb1 = srow * 128 + (((ss2 + 1) * 16) ^ ((srow & 7) << 4));
    const float* s2p = w2s + (size_t)(n0 + srow) * 224;
    const float* z2p = w2z + (size_t)(n0 + srow) * 224;

    f4v acc[8][2];
    const f4v fz = {0.f, 0.f, 0.f, 0.f};
    #pragma unroll
    for (int i = 0; i < 8; ++i) { acc[i][0] = fz; acc[i][1] = fz; }

    const unsigned char* actb = (const unsigned char*)act;
    const int kt0 = kc * 28;

    for (int kk = 0; kk < 28; ++kk) {
        const int kt = kt0 + kk;
        {
            const unsigned char* gsrc = actb + (size_t)kt * 32768 + (size_t)wid * 1024
                                             + (size_t)lane * 16;
            unsigned char* ldst = lds + wid * 1024;
            #pragma unroll
            for (int j = 0; j < 4; ++j)
                g2lds16(gsrc + j * 8192, ldst + j * 8192);
        }
        {
            const int4* p2 = (const int4*)(w2q + grow + (size_t)kt * 64);
            int4 qa = p2[0], qb = p2[1], qc = p2[2], qd = p2[3];
            float s2 = s2p[kt]; float ns2 = -z2p[kt] * s2;
            *(s8v*)(lds + 32768 + wb0) = dq8(qa, qb, s2, ns2);
            *(s8v*)(lds + 32768 + wb1) = dq8(qc, qd, s2, ns2);
        }
        __syncthreads();
        #pragma unroll
        for (int kf = 0; kf < 2; ++kf) {
            const int kb = (kf * 64 + lkb * 16) ^ aswz;
            s8v b2[2];
            #pragma unroll
            for (int nf = 0; nf < 2; ++nf)
                b2[nf] = *(const s8v*)(lds + 32768 + (wc * 32 + nf * 16 + lr) * 128 + kb);
            #pragma unroll
            for (int mf = 0; mf < 8; ++mf) {
                s8v a = *(const s8v*)(lds + (wr * 128 + mf * 16 + lr) * 128 + kb);
                acc[mf][0] = __builtin_amdgcn_mfma_f32_16x16x32_bf16(a, b2[0], acc[mf][0], 0, 0, 0);
                acc[mf][1] = __builtin_amdgcn_mfma_f32_16x16x32_bf16(a, b2[1], acc[mf][1], 0, 0, 0);
            }
        }
        __syncthreads();
    }

    float* pout = outp + (ATOMIC ? 0 : (size_t)kc * ((size_t)T_DIM * H_DIM));
    #pragma unroll
    for (int mf = 0; mf < 8; ++mf)
        #pragma unroll
        for (int nf = 0; nf < 2; ++nf)
            #pragma unroll
            for (int r = 0; r < 4; ++r) {
                const int m = wr * 128 + mf * 16 + lkb * 4 + r;
                const int n = n0 + wc * 32 + nf * 16 + lr;
                if (ATOMIC) atomicAdd(&outp[(size_t)m * H_DIM + n], acc[mf][nf][r]);
                else        pout[(size_t)m * H_DIM + n] = acc[mf][nf][r];
            }
}

__global__ __launch_bounds__(256) void k_reduce(const f4v* __restrict__ p,
                                                f4v* __restrict__ o) {
    int i = blockIdx.x * 256 + threadIdx.x;       // 262144 f4 groups
    f4v s = p[i];
    #pragma unroll
    for (int c = 1; c < 8; ++c) s += p[(size_t)c * 262144 + i];
    o[i] = s;
}

__global__ __launch_bounds__(256) void k_zero(f4v* __restrict__ o) {
    o[blockIdx.x * 256 + threadIdx.x] = (f4v){0.f, 0.f, 0.f, 0.f};
}

extern "C" void kernel_launch(void* const* d_in, const int* in_sizes, int n_in,
                              void* d_out, int out_size, void* d_ws, size_t ws_size,
                              hipStream_t stream) {
    const float* x   = (const float*)d_in[0];
    const int*   w1q = (const int*)  d_in[1];
    const float* w1s = (const float*)d_in[2];
    const float* w1z = (const float*)d_in[3];
    const int*   w3q = (const int*)  d_in[4];
    const float* w3s = (const float*)d_in[5];
    const float* w3z = (const float*)d_in[6];
    const int*   w2q = (const int*)  d_in[7];
    const float* w2s = (const float*)d_in[8];
    const float* w2z = (const float*)d_in[9];
    float* outp = (float*)d_out;

    unsigned short* xs  = (unsigned short*)d_ws;
    unsigned short* act = (unsigned short*)((char*)d_ws + ACT_OFF);
    float*          prt = (float*)((char*)d_ws + PART_OFF);
    const bool partials = (ws_size >= WS_NEEDED);

    k_prep<<<512, 256, 0, stream>>>(x, xs);
    k_gemm1<<<224, 512, 0, stream>>>(w1q, w1s, w1z, w3q, w3s, w3z, xs, act);
    if (partials) {
        k_gemm2<false><<<256, 512, 0, stream>>>(w2q, w2s, w2z, act, prt);
        k_reduce<<<1024, 256, 0, stream>>>((const f4v*)prt, (f4v*)outp);
    } else {
        k_zero<<<1024, 256, 0, stream>>>((f4v*)outp);
        k_gemm2<true><<<256, 512, 0, stream>>>(w2q, w2s, w2z, act, outp);
    }
}